// Round 1
// baseline (992.238 us; speedup 1.0000x reference)
//
#include <hip/hip_runtime.h>

#define BN_EPS 1e-4f

// ---------------- BN stats: per-channel sum & sumsq over N rows (C=32) ----
__global__ void stats_kernel(const float* __restrict__ x,
                             float* __restrict__ stats,   // [64] sum, sumsq
                             int total) {
    const int t = threadIdx.x;
    long idx = (long)blockIdx.x * 256 + t;
    const long stride = (long)gridDim.x * 256;
    float s = 0.f, q = 0.f;
    for (long e = idx; e < total; e += stride) {
        float v = x[e];
        s += v;
        q += v * v;
    }
    __shared__ float red[256];
    red[t] = s;
    __syncthreads();
    if (t < 32) {
        float a = 0.f;
#pragma unroll
        for (int g = 0; g < 8; ++g) a += red[g * 32 + t];
        atomicAdd(&stats[t], a);
    }
    __syncthreads();
    red[t] = q;
    __syncthreads();
    if (t < 32) {
        float a = 0.f;
#pragma unroll
        for (int g = 0; g < 8; ++g) a += red[g * 32 + t];
        atomicAdd(&stats[32 + t], a);
    }
}

// ---------------- fused bn_relu + gather-GEMM-scatter submanifold conv ----
// Block: 256 threads = 8 pair-groups of 32 lanes. lane = output channel.
// W[k] (32x32) staged in LDS. x row broadcast via double-buffered LDS.
template <int PAIRS>
__global__ void conv_kernel(const float* __restrict__ x,
                            const float* __restrict__ W,
                            const int* __restrict__ pin,
                            const int* __restrict__ pout,
                            const float* __restrict__ stats,
                            float* __restrict__ out,
                            int P, int N) {
    const int k = blockIdx.y;
    const int t = threadIdx.x;
    const int lane = t & 31;
    const int g = t >> 5;

    __shared__ float wlds[1024];
    __shared__ float xs[2][8][32];

    const float invN = 1.0f / (float)N;
    const float mu = stats[lane] * invN;
    const float var = stats[32 + lane] * invN - mu * mu;
    const float rsig = rsqrtf(var + BN_EPS);

    for (int idx = t; idx < 1024; idx += 256)
        wlds[idx] = W[k * 1024 + idx];
    __syncthreads();

    const int p0 = blockIdx.x * PAIRS;
    const int iters = PAIRS / 8;
    int buf = 0;
    const long kP = (long)k * P;

    for (int it = 0; it < iters; ++it) {
        const int p = p0 + it * 8 + g;
        int i = -1, o = -1;
        if (p < P) {
            i = pin[kP + p];
            if (i >= 0) o = pout[kP + p];
        }
        float xn = 0.f;
        if (i >= 0) {
            float v = x[(long)i * 32 + lane];
            xn = fmaxf((v - mu) * rsig, 0.f);
        }
        xs[buf][g][lane] = xn;
        __syncthreads();
        float y = 0.f;
#pragma unroll
        for (int j = 0; j < 32; ++j)
            y += xs[buf][g][j] * wlds[j * 32 + lane];
        if (o >= 0) atomicAdd(&out[(long)o * 32 + lane], y);
        buf ^= 1;  // double buffer: safe to overwrite other buffer next iter
    }
}

// ---------------- downsample scatter-mean ----------------
__global__ void ds_scatter(const float* __restrict__ xyz,
                           const int* __restrict__ batch,
                           const int* __restrict__ din,
                           const int* __restrict__ dout,
                           float* __restrict__ dsum,   // [M,4] xyz+batch
                           float* __restrict__ dcnt,   // [M]
                           int P2n) {
    int p = blockIdx.x * 256 + threadIdx.x;
    if (p >= P2n) return;
    int i = din[p];
    if (i < 0) return;
    int o = dout[p];
    atomicAdd(&dsum[o * 4 + 0], xyz[(long)i * 3 + 0]);
    atomicAdd(&dsum[o * 4 + 1], xyz[(long)i * 3 + 1]);
    atomicAdd(&dsum[o * 4 + 2], xyz[(long)i * 3 + 2]);
    atomicAdd(&dsum[o * 4 + 3], (float)batch[i]);
    atomicAdd(&dcnt[o], 1.0f);
}

__global__ void ds_finalize(const float* __restrict__ dsum,
                            const float* __restrict__ dcnt,
                            float* __restrict__ out_xyz,
                            float* __restrict__ out_batch,
                            int M) {
    int o = blockIdx.x * 256 + threadIdx.x;
    if (o >= M) return;
    float c = fmaxf(dcnt[o], 1.0f);
    float inv = 1.0f / c;
    out_xyz[(long)o * 3 + 0] = dsum[o * 4 + 0] * inv;
    out_xyz[(long)o * 3 + 1] = dsum[o * 4 + 1] * inv;
    out_xyz[(long)o * 3 + 2] = dsum[o * 4 + 2] * inv;
    out_batch[o] = dsum[o * 4 + 3] * inv;
}

extern "C" void kernel_launch(void* const* d_in, const int* in_sizes, int n_in,
                              void* d_out, int out_size, void* d_ws, size_t ws_size,
                              hipStream_t stream) {
    const float* feats = (const float*)d_in[0];
    const float* xyz   = (const float*)d_in[1];
    const int*   batch = (const int*)d_in[2];
    const int*   pin   = (const int*)d_in[3];
    const int*   pout  = (const int*)d_in[4];
    const int*   dsin  = (const int*)d_in[5];
    const int*   dsout = (const int*)d_in[6];
    const float* W1    = (const float*)d_in[7];
    const float* W2    = (const float*)d_in[8];

    const int N   = in_sizes[0] / 32;
    const int K   = 27;
    const int P   = in_sizes[3] / K;
    const int P2n = in_sizes[5];
    const int M   = (out_size - N * 32) / 4;

    float* ws = (float*)d_ws;
    float* stats1 = ws;           // 64
    float* stats2 = ws + 64;      // 64
    float* dsum   = ws + 128;     // 4*M
    float* dcnt   = dsum + (size_t)4 * M;  // M
    size_t off = (128 + 5 * (size_t)M + 255) & ~(size_t)255;
    float* hacc = ws + off;       // N*32

    const size_t used_bytes = (off + (size_t)N * 32) * sizeof(float);
    hipMemsetAsync(d_ws, 0, used_bytes, stream);

    float* out = (float*)d_out;
    // identity: out = feats (conv2 accumulates on top)
    hipMemcpyAsync(out, feats, (size_t)N * 32 * sizeof(float),
                   hipMemcpyDeviceToDevice, stream);

    // BN1 stats on feats
    stats_kernel<<<1024, 256, 0, stream>>>(feats, stats1, N * 32);

    // conv1: bn_relu(feats) -> W1 -> hacc
    constexpr int PAIRS = 512;
    dim3 cgrid((P + PAIRS - 1) / PAIRS, K);
    conv_kernel<PAIRS><<<cgrid, 256, 0, stream>>>(feats, W1, pin, pout,
                                                  stats1, hacc, P, N);

    // BN2 stats on hacc
    stats_kernel<<<1024, 256, 0, stream>>>(hacc, stats2, N * 32);

    // conv2: bn_relu(hacc) -> W2 -> accumulate into out (already = feats)
    conv_kernel<PAIRS><<<cgrid, 256, 0, stream>>>(hacc, W2, pin, pout,
                                                  stats2, out, P, N);

    // downsample scatter-mean
    ds_scatter<<<(P2n + 255) / 256, 256, 0, stream>>>(xyz, batch, dsin, dsout,
                                                      dsum, dcnt, P2n);
    ds_finalize<<<(M + 255) / 256, 256, 0, stream>>>(dsum, dcnt,
                                                     out + (size_t)N * 32,
                                                     out + (size_t)N * 32 + (size_t)3 * M,
                                                     M);
}

// Round 2
// 898.154 us; speedup vs baseline: 1.1048x; 1.1048x over previous
//
#include <hip/hip_runtime.h>

#define BN_EPS 1e-4f

typedef __attribute__((ext_vector_type(8))) short short8;   // 8 bf16 (4 VGPRs)
typedef __attribute__((ext_vector_type(4))) float f32x4;    // MFMA acc
typedef __attribute__((ext_vector_type(4))) float floatv4;

// float -> bf16 bits, round-to-nearest-even
static __device__ __forceinline__ short f2bf(float f) {
    unsigned u = __float_as_uint(f);
    unsigned r = (u + 0x7FFFu + ((u >> 16) & 1u)) >> 16;
    return (short)r;
}

// ---------------- BN stats: per-channel sum & sumsq over N rows (C=32) ----
__global__ void stats_kernel(const float* __restrict__ x,
                             float* __restrict__ stats,   // [64] sum, sumsq
                             int total) {
    const int t = threadIdx.x;
    long idx = (long)blockIdx.x * 256 + t;
    const long stride = (long)gridDim.x * 256;
    float s = 0.f, q = 0.f;
    for (long e = idx; e < total; e += stride) {
        float v = x[e];
        s += v;
        q += v * v;
    }
    __shared__ float red[256];
    red[t] = s;
    __syncthreads();
    if (t < 32) {
        float a = 0.f;
#pragma unroll
        for (int g = 0; g < 8; ++g) a += red[g * 32 + t];
        atomicAdd(&stats[t], a);
    }
    __syncthreads();
    red[t] = q;
    __syncthreads();
    if (t < 32) {
        float a = 0.f;
#pragma unroll
        for (int g = 0; g < 8; ++g) a += red[g * 32 + t];
        atomicAdd(&stats[32 + t], a);
    }
}

// ------- fused bn_relu + gather + MFMA GEMM + atomic scatter, per k -------
// Block = 256 threads = 4 waves. Each wave owns TPW tiles of 16 pairs.
// MFMA 16x16x32 bf16: A = 16 gathered bn_relu'd x-rows, B = W[k] (regs).
// A-frag: row = lane&15, k-chunk = (lane>>4)*8..+8 (any consistent K-perm
// cancels between A and B). C/D: col = lane&15, row = (lane>>4)*4+reg (m89).
template <int TPW>
__global__ void conv_mfma(const float* __restrict__ x,
                          const float* __restrict__ W,
                          const int* __restrict__ pin,
                          const int* __restrict__ pout,
                          const float* __restrict__ stats,
                          float* __restrict__ out,
                          int P, int N, int tilesPerK) {
    const int k   = blockIdx.y;
    const int t   = threadIdx.x;
    const int w   = t >> 6;
    const int l   = t & 63;
    const int m16 = l & 15;   // A-row-within-tile / C col (cout)
    const int iq  = l >> 4;   // k-quad: channels iq*8 .. iq*8+7

    const float invN = 1.0f / (float)N;
    float rs8[8], bi8[8];     // x_norm = x*rs + bias, then relu
#pragma unroll
    for (int j = 0; j < 8; ++j) {
        int c = iq * 8 + j;
        float mu  = stats[c] * invN;
        float var = stats[32 + c] * invN - mu * mu;
        float rs  = rsqrtf(var + BN_EPS);
        rs8[j] = rs;
        bi8[j] = -mu * rs;
    }

    // B fragments for this k: B[kk][n] = W[k][cin=kk][cout=n]
    const float* Wk = W + k * 1024;
    short8 b0, b1;
#pragma unroll
    for (int j = 0; j < 8; ++j) {
        b0[j] = f2bf(Wk[(iq * 8 + j) * 32 + m16]);
        b1[j] = f2bf(Wk[(iq * 8 + j) * 32 + 16 + m16]);
    }

    const long kP = (long)k * P;
    const int tile0 = (blockIdx.x * 4 + w) * TPW;

    for (int tt = 0; tt < TPW; ++tt) {
        const int tile = tile0 + tt;
        if (tile >= tilesPerK) break;
        const int p0 = tile * 16;

        // ---- gather A row (pair p0+m16), channels iq*8..+7 ----
        short8 a = {0, 0, 0, 0, 0, 0, 0, 0};
        const int pa = p0 + m16;
        int ia = (pa < P) ? pin[kP + pa] : -1;
        if (ia >= 0) {
            const float* xr = x + (long)ia * 32 + iq * 8;
            floatv4 v0 = *(const floatv4*)xr;
            floatv4 v1 = *(const floatv4*)(xr + 4);
#pragma unroll
            for (int j = 0; j < 4; ++j) {
                a[j]     = f2bf(fmaxf(fmaf(v0[j], rs8[j],     bi8[j]),     0.f));
                a[4 + j] = f2bf(fmaxf(fmaf(v1[j], rs8[4 + j], bi8[4 + j]), 0.f));
            }
        }

        f32x4 c0 = {0.f, 0.f, 0.f, 0.f};
        f32x4 c1 = {0.f, 0.f, 0.f, 0.f};
        c0 = __builtin_amdgcn_mfma_f32_16x16x32_bf16(a, b0, c0, 0, 0, 0);
        c1 = __builtin_amdgcn_mfma_f32_16x16x32_bf16(a, b1, c1, 0, 0, 0);

        // ---- scatter rows iq*4 + j ----
#pragma unroll
        for (int j = 0; j < 4; ++j) {
            const int pr = p0 + iq * 4 + j;
            if (pr < P) {
                int pi = pin[kP + pr];
                if (pi >= 0) {
                    long base = (long)pout[kP + pr] * 32;
                    atomicAdd(&out[base + m16],      c0[j]);
                    atomicAdd(&out[base + 16 + m16], c1[j]);
                }
            }
        }
    }
}

// ---------------- downsample scatter-mean ----------------
__global__ void ds_scatter(const float* __restrict__ xyz,
                           const int* __restrict__ batch,
                           const int* __restrict__ din,
                           const int* __restrict__ dout,
                           float* __restrict__ dsum,   // [M,4] xyz+batch
                           float* __restrict__ dcnt,   // [M]
                           int P2n) {
    int p = blockIdx.x * 256 + threadIdx.x;
    if (p >= P2n) return;
    int i = din[p];
    if (i < 0) return;
    int o = dout[p];
    atomicAdd(&dsum[o * 4 + 0], xyz[(long)i * 3 + 0]);
    atomicAdd(&dsum[o * 4 + 1], xyz[(long)i * 3 + 1]);
    atomicAdd(&dsum[o * 4 + 2], xyz[(long)i * 3 + 2]);
    atomicAdd(&dsum[o * 4 + 3], (float)batch[i]);
    atomicAdd(&dcnt[o], 1.0f);
}

__global__ void ds_finalize(const float* __restrict__ dsum,
                            const float* __restrict__ dcnt,
                            float* __restrict__ out_xyz,
                            float* __restrict__ out_batch,
                            int M) {
    int o = blockIdx.x * 256 + threadIdx.x;
    if (o >= M) return;
    float c = fmaxf(dcnt[o], 1.0f);
    float inv = 1.0f / c;
    out_xyz[(long)o * 3 + 0] = dsum[o * 4 + 0] * inv;
    out_xyz[(long)o * 3 + 1] = dsum[o * 4 + 1] * inv;
    out_xyz[(long)o * 3 + 2] = dsum[o * 4 + 2] * inv;
    out_batch[o] = dsum[o * 4 + 3] * inv;
}

extern "C" void kernel_launch(void* const* d_in, const int* in_sizes, int n_in,
                              void* d_out, int out_size, void* d_ws, size_t ws_size,
                              hipStream_t stream) {
    const float* feats = (const float*)d_in[0];
    const float* xyz   = (const float*)d_in[1];
    const int*   batch = (const int*)d_in[2];
    const int*   pin   = (const int*)d_in[3];
    const int*   pout  = (const int*)d_in[4];
    const int*   dsin  = (const int*)d_in[5];
    const int*   dsout = (const int*)d_in[6];
    const float* W1    = (const float*)d_in[7];
    const float* W2    = (const float*)d_in[8];

    const int N   = in_sizes[0] / 32;
    const int K   = 27;
    const int P   = in_sizes[3] / K;
    const int P2n = in_sizes[5];
    const int M   = (out_size - N * 32) / 4;

    float* ws = (float*)d_ws;
    float* stats1 = ws;           // 64
    float* stats2 = ws + 64;      // 64
    float* dsum   = ws + 128;     // 4*M
    float* dcnt   = dsum + (size_t)4 * M;  // M
    size_t off = (128 + 5 * (size_t)M + 255) & ~(size_t)255;
    float* hacc = ws + off;       // N*32

    const size_t used_bytes = (off + (size_t)N * 32) * sizeof(float);
    hipMemsetAsync(d_ws, 0, used_bytes, stream);

    float* out = (float*)d_out;
    // identity: out = feats (conv2 accumulates on top)
    hipMemcpyAsync(out, feats, (size_t)N * 32 * sizeof(float),
                   hipMemcpyDeviceToDevice, stream);

    // BN1 stats on feats
    stats_kernel<<<1024, 256, 0, stream>>>(feats, stats1, N * 32);

    constexpr int TPW = 4;
    const int tilesPerK = (P + 15) / 16;
    dim3 cgrid((tilesPerK + 4 * TPW - 1) / (4 * TPW), K);

    // conv1: bn_relu(feats) -> W1 -> hacc
    conv_mfma<TPW><<<cgrid, 256, 0, stream>>>(feats, W1, pin, pout,
                                              stats1, hacc, P, N, tilesPerK);

    // BN2 stats on hacc
    stats_kernel<<<1024, 256, 0, stream>>>(hacc, stats2, N * 32);

    // conv2: bn_relu(hacc) -> W2 -> accumulate into out (already = feats)
    conv_mfma<TPW><<<cgrid, 256, 0, stream>>>(hacc, W2, pin, pout,
                                              stats2, out, P, N, tilesPerK);

    // downsample scatter-mean
    ds_scatter<<<(P2n + 255) / 256, 256, 0, stream>>>(xyz, batch, dsin, dsout,
                                                      dsum, dcnt, P2n);
    ds_finalize<<<(M + 255) / 256, 256, 0, stream>>>(dsum, dcnt,
                                                     out + (size_t)N * 32,
                                                     out + (size_t)N * 32 + (size_t)3 * M,
                                                     M);
}